// Round 1
// baseline (203.702 us; speedup 1.0000x reference)
//
#include <hip/hip_runtime.h>

// Domain transform recursive filter, [4,32,512,512] f32.
// c_i = -sqrt(2)/sigma_i ; sigma0 = 120*sqrt(0.2), sigma1 = 60*sqrt(0.2)
// c0 = -sqrt(10)/120, c1 = 2*c0
#define C0F (-0.026352313834736496f)
#define C1F (-0.052704627669472993f)

#define NB 4
#define NC 32
#define NH 512
#define NW 512

// ---------------- V-table precompute: V = exp(c * (1 + 150*edge)) -------------
__global__ __launch_bounds__(256) void vtab_kernel(const float* __restrict__ edge,
                                                   float* __restrict__ v0,
                                                   float* __restrict__ v1) {
    int i = blockIdx.x * 256 + threadIdx.x;            // float4 index, 262144 total
    float4 e = reinterpret_cast<const float4*>(edge)[i];
    float dx = 1.f + 150.f * e.x;
    float dy = 1.f + 150.f * e.y;
    float dz = 1.f + 150.f * e.z;
    float dw = 1.f + 150.f * e.w;
    float4 a0, a1;
    a0.x = expf(C0F * dx); a0.y = expf(C0F * dy); a0.z = expf(C0F * dz); a0.w = expf(C0F * dw);
    a1.x = expf(C1F * dx); a1.y = expf(C1F * dy); a1.z = expf(C1F * dz); a1.w = expf(C1F * dw);
    reinterpret_cast<float4*>(v0)[i] = a0;
    reinterpret_cast<float4*>(v1)[i] = a1;
}

// ---------------- Horizontal pass: one wave per row, scan in registers --------
__global__ __launch_bounds__(256) void hpass_kernel(const float* __restrict__ src,
                                                    float* __restrict__ dst,
                                                    const float* __restrict__ vt) {
    const int lane = threadIdx.x & 63;
    const int wv   = threadIdx.x >> 6;
    const int row  = (blockIdx.x << 2) + wv;           // 0..65535
    const int h    = row & (NH - 1);
    const int bc   = row >> 9;                          // b*32 + c
    const int b    = bc >> 5;
    const float* srow = src + ((size_t)row << 9);
    float*       drow = dst + ((size_t)row << 9);
    const float* vrow = vt + (((size_t)(b << 9) + h) << 9);
    const int g0 = lane << 3;

    float x[8], v[8];
    {
        float4 p0 = *reinterpret_cast<const float4*>(srow + g0);
        float4 p1 = *reinterpret_cast<const float4*>(srow + g0 + 4);
        float4 q0 = *reinterpret_cast<const float4*>(vrow + g0);
        float4 q1 = *reinterpret_cast<const float4*>(vrow + g0 + 4);
        x[0]=p0.x; x[1]=p0.y; x[2]=p0.z; x[3]=p0.w;
        x[4]=p1.x; x[5]=p1.y; x[6]=p1.z; x[7]=p1.w;
        v[0]=q0.x; v[1]=q0.y; v[2]=q0.z; v[3]=q0.w;
        v[4]=q1.x; v[5]=q1.y; v[6]=q1.z; v[7]=q1.w;
    }

    // ---- forward: x_i = a_i x_{i-1} + (1-a_i) img_i, a_0(global)=0 ----
    float A = 1.f, Bv = 0.f;
    #pragma unroll
    for (int i = 0; i < 8; ++i) {
        float a = v[i];
        if (lane == 0 && i == 0) a = 0.f;
        Bv = a * Bv + (1.f - a) * x[i];
        A  = a * A;
    }
    #pragma unroll
    for (int d = 1; d < 64; d <<= 1) {         // inclusive scan, compose cur∘prev
        float Ap = __shfl_up(A, d);
        float Bp = __shfl_up(Bv, d);
        if (lane >= d) { Bv = A * Bp + Bv; A = A * Ap; }
    }
    float carry = __shfl_up(Bv, 1);
    if (lane == 0) carry = 0.f;
    float xp = carry;
    #pragma unroll
    for (int i = 0; i < 8; ++i) {
        float a = v[i];
        if (lane == 0 && i == 0) a = 0.f;
        xp = a * xp + (1.f - a) * x[i];
        x[i] = xp;
    }

    // ---- backward: y_i = a'_i y_{i+1} + (1-a'_i) x_i, a'_i = V_{i+1}, a'_511=0
    float vn = __shfl_down(v[0], 1);           // lane+1's v[0]
    A = 1.f; Bv = 0.f;
    #pragma unroll
    for (int i = 7; i >= 0; --i) {
        float a = (i < 7) ? v[i + 1] : ((lane == 63) ? 0.f : vn);
        Bv = a * Bv + (1.f - a) * x[i];
        A  = a * A;
    }
    #pragma unroll
    for (int d = 1; d < 64; d <<= 1) {         // descending inclusive scan
        float Ap = __shfl_down(A, d);
        float Bp = __shfl_down(Bv, d);
        if (lane < 64 - d) { Bv = A * Bp + Bv; A = A * Ap; }
    }
    float cb = __shfl_down(Bv, 1);
    if (lane == 63) cb = 0.f;
    float yn = cb;
    #pragma unroll
    for (int i = 7; i >= 0; --i) {
        float a = (i < 7) ? v[i + 1] : ((lane == 63) ? 0.f : vn);
        yn = a * yn + (1.f - a) * x[i];
        x[i] = yn;
    }

    *reinterpret_cast<float4*>(drow + g0)     = make_float4(x[0], x[1], x[2], x[3]);
    *reinterpret_cast<float4*>(drow + g0 + 4) = make_float4(x[4], x[5], x[6], x[7]);
}

// ---------------- Vertical pass: in place; 32 cols x 16 h-chunks of 32 rows ---
#define VROWS 32
__global__ __launch_bounds__(512) void vpass_kernel(float* __restrict__ img,
                                                    const float* __restrict__ vt) {
    const int col   = threadIdx.x & 31;
    const int hc    = threadIdx.x >> 5;        // 0..15
    const int strip = blockIdx.x & 15;         // 16 strips of 32 columns
    const int bc    = blockIdx.x >> 4;         // 0..127
    const int b     = bc >> 5;
    const int w     = (strip << 5) + col;
    float*       base = img + ((size_t)bc << 18) + w;
    const float* vb   = vt  + ((size_t)b  << 18) + w;
    const int h0 = hc << 5;

    float x[VROWS], v[VROWS];
    #pragma unroll
    for (int i = 0; i < VROWS; ++i) x[i] = base[(size_t)(h0 + i) << 9];
    #pragma unroll
    for (int i = 0; i < VROWS; ++i) v[i] = vb[(size_t)(h0 + i) << 9];

    __shared__ float sA[16][32], sB[16][32], sC[16][32], sV[16][32];

    // ---- forward ----
    float A = 1.f, Bv = 0.f;
    #pragma unroll
    for (int i = 0; i < VROWS; ++i) {
        float a = v[i];
        if (hc == 0 && i == 0) a = 0.f;        // global h == 0
        Bv = a * Bv + (1.f - a) * x[i];
        A  = a * A;
    }
    sA[hc][col] = A; sB[hc][col] = Bv;
    __syncthreads();
    if (hc == 0) {                              // serial scan of 16 chunk maps
        float c = 0.f;
        #pragma unroll
        for (int k = 0; k < 16; ++k) {
            float a_ = sA[k][col], b_ = sB[k][col];
            sC[k][col] = c;                     // carry INTO chunk k
            c = a_ * c + b_;
        }
    }
    __syncthreads();
    float xp = sC[hc][col];
    #pragma unroll
    for (int i = 0; i < VROWS; ++i) {
        float a = v[i];
        if (hc == 0 && i == 0) a = 0.f;
        xp = a * xp + (1.f - a) * x[i];
        x[i] = xp;
    }
    sV[hc][col] = v[0];
    __syncthreads();
    float vnext = (hc < 15) ? sV[hc + 1][col] : 0.f;

    // ---- backward ----
    A = 1.f; Bv = 0.f;
    #pragma unroll
    for (int i = VROWS - 1; i >= 0; --i) {
        float a = (i < VROWS - 1) ? v[i + 1] : ((hc == 15) ? 0.f : vnext);
        Bv = a * Bv + (1.f - a) * x[i];
        A  = a * A;
    }
    sA[hc][col] = A; sB[hc][col] = Bv;
    __syncthreads();
    if (hc == 0) {
        float c = 0.f;
        #pragma unroll
        for (int k = 15; k >= 0; --k) {
            float a_ = sA[k][col], b_ = sB[k][col];
            sC[k][col] = c;                     // carry INTO chunk k (y below it)
            c = a_ * c + b_;
        }
    }
    __syncthreads();
    float yn = sC[hc][col];
    #pragma unroll
    for (int i = VROWS - 1; i >= 0; --i) {
        float a = (i < VROWS - 1) ? v[i + 1] : ((hc == 15) ? 0.f : vnext);
        yn = a * yn + (1.f - a) * x[i];
        x[i] = yn;
    }
    #pragma unroll
    for (int i = 0; i < VROWS; ++i) base[(size_t)(h0 + i) << 9] = x[i];
}

extern "C" void kernel_launch(void* const* d_in, const int* in_sizes, int n_in,
                              void* d_out, int out_size, void* d_ws, size_t ws_size,
                              hipStream_t stream) {
    const float* img  = (const float*)d_in[0];   // [4,32,512,512]
    const float* edge = (const float*)d_in[1];   // [4,1,512,512]
    float* out = (float*)d_out;
    float* v0 = (float*)d_ws;                    // 4 MB
    float* v1 = v0 + (size_t)NB * NH * NW;       // 4 MB

    vtab_kernel<<<(NB * NH * NW) / (256 * 4), 256, 0, stream>>>(edge, v0, v1);

    // iteration 0 (sigma0 -> v0)
    hpass_kernel<<<(NB * NC * NH) / 4, 256, 0, stream>>>(img, out, v0);
    vpass_kernel<<<NB * NC * (NW / 32), 512, 0, stream>>>(out, v0);
    // iteration 1 (sigma1 -> v1)
    hpass_kernel<<<(NB * NC * NH) / 4, 256, 0, stream>>>(out, out, v1);
    vpass_kernel<<<NB * NC * (NW / 32), 512, 0, stream>>>(out, v1);
}

// Round 2
// 186.623 us; speedup vs baseline: 1.0915x; 1.0915x over previous
//
#include <hip/hip_runtime.h>

// Domain transform recursive filter, [4,32,512,512] f32.
// c_i = -sqrt(2)/sigma_i ; sigma0 = 60*sqrt3*2/sqrt(15), sigma1 = 60*sqrt3/sqrt(15)
#define C0F (-0.026352313834736496f)
#define C1F (-0.052704627669472993f)

#define NB 4
#define NC 32
#define NH 512
#define NW 512

typedef _Float16 h16;
typedef __attribute__((ext_vector_type(8))) _Float16 f16x8;

// ---- 8-element load/store helpers (f32 or f16 storage, f32 compute) ---------
__device__ __forceinline__ void load8(const float* p, float* x) {
    float4 a = *reinterpret_cast<const float4*>(p);
    float4 b = *reinterpret_cast<const float4*>(p + 4);
    x[0]=a.x; x[1]=a.y; x[2]=a.z; x[3]=a.w;
    x[4]=b.x; x[5]=b.y; x[6]=b.z; x[7]=b.w;
}
__device__ __forceinline__ void load8(const h16* p, float* x) {
    f16x8 h = *reinterpret_cast<const f16x8*>(p);
    #pragma unroll
    for (int i = 0; i < 8; ++i) x[i] = (float)h[i];
}
__device__ __forceinline__ void store8(float* p, const float* x) {
    *reinterpret_cast<float4*>(p)     = make_float4(x[0],x[1],x[2],x[3]);
    *reinterpret_cast<float4*>(p + 4) = make_float4(x[4],x[5],x[6],x[7]);
}
__device__ __forceinline__ void store8(h16* p, const float* x) {
    f16x8 h;
    #pragma unroll
    for (int i = 0; i < 8; ++i) h[i] = (h16)x[i];
    *reinterpret_cast<f16x8*>(p) = h;
}

// ---------------- V-table precompute: V = exp(c * (1 + 150*edge)) -------------
__global__ __launch_bounds__(256) void vtab_kernel(const float* __restrict__ edge,
                                                   float* __restrict__ v0,
                                                   float* __restrict__ v1) {
    int i = blockIdx.x * 256 + threadIdx.x;            // float4 index, 262144 total
    float4 e = reinterpret_cast<const float4*>(edge)[i];
    float dx = 1.f + 150.f * e.x;
    float dy = 1.f + 150.f * e.y;
    float dz = 1.f + 150.f * e.z;
    float dw = 1.f + 150.f * e.w;
    float4 a0, a1;
    a0.x = expf(C0F * dx); a0.y = expf(C0F * dy); a0.z = expf(C0F * dz); a0.w = expf(C0F * dw);
    a1.x = expf(C1F * dx); a1.y = expf(C1F * dy); a1.z = expf(C1F * dz); a1.w = expf(C1F * dw);
    reinterpret_cast<float4*>(v0)[i] = a0;
    reinterpret_cast<float4*>(v1)[i] = a1;
}

// ---------------- Horizontal pass: one wave per row, scan in registers --------
template <typename ST, typename DT>
__global__ __launch_bounds__(256) void hpass_kernel(const ST* __restrict__ src,
                                                    DT* __restrict__ dst,
                                                    const float* __restrict__ vt) {
    const int lane = threadIdx.x & 63;
    const int wv   = threadIdx.x >> 6;
    const int row  = (blockIdx.x << 2) + wv;           // 0..65535
    const int h    = row & (NH - 1);
    const int bc   = row >> 9;                          // b*32 + c
    const int b    = bc >> 5;
    const ST* srow = src + ((size_t)row << 9);
    DT*       drow = dst + ((size_t)row << 9);
    const float* vrow = vt + (((size_t)(b << 9) + h) << 9);
    const int g0 = lane << 3;

    float x[8], v[8];
    load8(srow + g0, x);
    load8(vrow + g0, v);

    // ---- forward: x_i = a_i x_{i-1} + (1-a_i) img_i, a_0(global)=0 ----
    float A = 1.f, Bv = 0.f;
    #pragma unroll
    for (int i = 0; i < 8; ++i) {
        float a = v[i];
        if (lane == 0 && i == 0) a = 0.f;
        Bv = a * Bv + (1.f - a) * x[i];
        A  = a * A;
    }
    #pragma unroll
    for (int d = 1; d < 64; d <<= 1) {         // inclusive scan, compose cur∘prev
        float Ap = __shfl_up(A, d);
        float Bp = __shfl_up(Bv, d);
        if (lane >= d) { Bv = A * Bp + Bv; A = A * Ap; }
    }
    float carry = __shfl_up(Bv, 1);
    if (lane == 0) carry = 0.f;
    float xp = carry;
    #pragma unroll
    for (int i = 0; i < 8; ++i) {
        float a = v[i];
        if (lane == 0 && i == 0) a = 0.f;
        xp = a * xp + (1.f - a) * x[i];
        x[i] = xp;
    }

    // ---- backward: y_i = a'_i y_{i+1} + (1-a'_i) x_i, a'_i = V_{i+1}, a'_511=0
    float vn = __shfl_down(v[0], 1);           // lane+1's v[0]
    float A2 = 1.f, B2 = 0.f;
    #pragma unroll
    for (int i = 7; i >= 0; --i) {
        float a = (i < 7) ? v[i + 1] : ((lane == 63) ? 0.f : vn);
        B2 = a * B2 + (1.f - a) * x[i];
        A2 = a * A2;
    }
    #pragma unroll
    for (int d = 1; d < 64; d <<= 1) {         // descending inclusive scan
        float Ap = __shfl_down(A2, d);
        float Bp = __shfl_down(B2, d);
        if (lane < 64 - d) { B2 = A2 * Bp + B2; A2 = A2 * Ap; }
    }
    float cb = __shfl_down(B2, 1);
    if (lane == 63) cb = 0.f;
    float yn = cb;
    #pragma unroll
    for (int i = 7; i >= 0; --i) {
        float a = (i < 7) ? v[i + 1] : ((lane == 63) ? 0.f : vn);
        yn = a * yn + (1.f - a) * x[i];
        x[i] = yn;
    }

    store8(drow + g0, x);
}

// ---------------- Vertical pass: 32 cols x 16 h-chunks of 32 rows -------------
// Safe in place (src==dst) per-block: block reads its tile fully before writing.
#define VROWS 32
template <typename ST, typename DT>
__global__ __launch_bounds__(512) void vpass_kernel(const ST* __restrict__ src,
                                                    DT* __restrict__ dst,
                                                    const float* __restrict__ vt) {
    const int col   = threadIdx.x & 31;
    const int hc    = threadIdx.x >> 5;        // 0..15
    const int strip = blockIdx.x & 15;         // 16 strips of 32 columns
    const int bc    = blockIdx.x >> 4;         // 0..127
    const int b     = bc >> 5;
    const int w     = (strip << 5) + col;
    const ST*    sbase = src + ((size_t)bc << 18) + w;
    DT*          dbase = dst + ((size_t)bc << 18) + w;
    const float* vb    = vt  + ((size_t)b  << 18) + w;
    const int h0 = hc << 5;

    float x[VROWS], v[VROWS];
    #pragma unroll
    for (int i = 0; i < VROWS; ++i) x[i] = (float)sbase[(size_t)(h0 + i) << 9];
    #pragma unroll
    for (int i = 0; i < VROWS; ++i) v[i] = vb[(size_t)(h0 + i) << 9];

    __shared__ float sA[16][32], sB[16][32], sC[16][32], sV[16][32];

    // ---- forward ----
    float A = 1.f, Bv = 0.f;
    #pragma unroll
    for (int i = 0; i < VROWS; ++i) {
        float a = v[i];
        if (hc == 0 && i == 0) a = 0.f;        // global h == 0
        Bv = a * Bv + (1.f - a) * x[i];
        A  = a * A;
    }
    sA[hc][col] = A; sB[hc][col] = Bv;
    __syncthreads();
    if (hc == 0) {                              // serial scan of 16 chunk maps
        float c = 0.f;
        #pragma unroll
        for (int k = 0; k < 16; ++k) {
            float a_ = sA[k][col], b_ = sB[k][col];
            sC[k][col] = c;                     // carry INTO chunk k
            c = a_ * c + b_;
        }
    }
    __syncthreads();
    float xp = sC[hc][col];
    #pragma unroll
    for (int i = 0; i < VROWS; ++i) {
        float a = v[i];
        if (hc == 0 && i == 0) a = 0.f;
        xp = a * xp + (1.f - a) * x[i];
        x[i] = xp;
    }
    sV[hc][col] = v[0];
    __syncthreads();
    float vnext = (hc < 15) ? sV[hc + 1][col] : 0.f;

    // ---- backward ----
    A = 1.f; Bv = 0.f;
    #pragma unroll
    for (int i = VROWS - 1; i >= 0; --i) {
        float a = (i < VROWS - 1) ? v[i + 1] : ((hc == 15) ? 0.f : vnext);
        Bv = a * Bv + (1.f - a) * x[i];
        A  = a * A;
    }
    sA[hc][col] = A; sB[hc][col] = Bv;
    __syncthreads();
    if (hc == 0) {
        float c = 0.f;
        #pragma unroll
        for (int k = 15; k >= 0; --k) {
            float a_ = sA[k][col], b_ = sB[k][col];
            sC[k][col] = c;                     // carry INTO chunk k (y below it)
            c = a_ * c + b_;
        }
    }
    __syncthreads();
    float yn = sC[hc][col];
    #pragma unroll
    for (int i = VROWS - 1; i >= 0; --i) {
        float a = (i < VROWS - 1) ? v[i + 1] : ((hc == 15) ? 0.f : vnext);
        yn = a * yn + (1.f - a) * x[i];
        x[i] = yn;
    }
    #pragma unroll
    for (int i = 0; i < VROWS; ++i) dbase[(size_t)(h0 + i) << 9] = (DT)x[i];
}

extern "C" void kernel_launch(void* const* d_in, const int* in_sizes, int n_in,
                              void* d_out, int out_size, void* d_ws, size_t ws_size,
                              hipStream_t stream) {
    const float* img  = (const float*)d_in[0];   // [4,32,512,512]
    const float* edge = (const float*)d_in[1];   // [4,1,512,512]
    float* out = (float*)d_out;

    const size_t NBHW  = (size_t)NB * NH * NW;           // 1M elems (4 MB f32)
    const size_t NTOT  = (size_t)NB * NC * NH * NW;      // 32M elems
    float* v0 = (float*)d_ws;                            // 4 MB
    float* v1 = v0 + NBHW;                               // 4 MB
    h16*   tmp = (h16*)(v1 + NBHW);                      // 64 MB (fp16 intermediate)
    const size_t need = NBHW * 8 + NTOT * 2;

    vtab_kernel<<<(int)(NBHW / (256 * 4)), 256, 0, stream>>>(edge, v0, v1);

    const int HG = NB * NC * NH / 4;      // 16384 blocks of 256
    const int VG = NB * NC * (NW / 32);   // 2048 blocks of 512

    if (ws_size >= need) {
        // fp16 intermediates: halves traffic of the 3 inner hand-offs
        hpass_kernel<float, h16><<<HG, 256, 0, stream>>>(img, tmp, v0);
        vpass_kernel<h16, h16><<<VG, 512, 0, stream>>>(tmp, tmp, v0);
        hpass_kernel<h16, h16><<<HG, 256, 0, stream>>>(tmp, tmp, v1);
        vpass_kernel<h16, float><<<VG, 512, 0, stream>>>(tmp, out, v1);
    } else {
        // f32 fallback (proven path)
        hpass_kernel<float, float><<<HG, 256, 0, stream>>>(img, out, v0);
        vpass_kernel<float, float><<<VG, 512, 0, stream>>>(out, out, v0);
        hpass_kernel<float, float><<<HG, 256, 0, stream>>>(out, out, v1);
        vpass_kernel<float, float><<<VG, 512, 0, stream>>>(out, out, v1);
    }
}

// Round 4
// 160.781 us; speedup vs baseline: 1.2670x; 1.1607x over previous
//
#include <hip/hip_runtime.h>

// Domain transform recursive filter, [4,32,512,512] f32.
// All four filter passes (H,V,H,V) are executed as ROW scans; each pass
// writes its output transposed via an LDS tile so the next pass again
// reads coalesced rows. Coefficient tables precomputed in both layouts.
#define C0F (-0.026352313834736496f)
#define C1F (-0.052704627669472993f)

#define NB 4
#define NC 32
#define NH 512
#define NW 512

typedef _Float16 h16;
typedef __attribute__((ext_vector_type(8))) _Float16 f16x8;

// ---- 8-element load/store helpers (f32 or f16 storage, f32 compute) ---------
__device__ __forceinline__ void load8(const float* p, float* x) {
    float4 a = *reinterpret_cast<const float4*>(p);
    float4 b = *reinterpret_cast<const float4*>(p + 4);
    x[0]=a.x; x[1]=a.y; x[2]=a.z; x[3]=a.w;
    x[4]=b.x; x[5]=b.y; x[6]=b.z; x[7]=b.w;
}
__device__ __forceinline__ void load8(const h16* p, float* x) {
    f16x8 h = *reinterpret_cast<const f16x8*>(p);
    #pragma unroll
    for (int i = 0; i < 8; ++i) x[i] = (float)h[i];
}
__device__ __forceinline__ void store8(float* p, const float* x) {
    *reinterpret_cast<float4*>(p)     = make_float4(x[0],x[1],x[2],x[3]);
    *reinterpret_cast<float4*>(p + 4) = make_float4(x[4],x[5],x[6],x[7]);
}
__device__ __forceinline__ void store8(h16* p, const float* x) {
    f16x8 h;
    #pragma unroll
    for (int i = 0; i < 8; ++i) h[i] = (h16)x[i];
    *reinterpret_cast<f16x8*>(p) = h;
}

// ---- wave row scan: forward+backward first-order recursive filter ----------
__device__ __forceinline__ void row_scan(float (&x)[8], const float (&v)[8], int lane) {
    // forward: x_i = a_i x_{i-1} + (1-a_i) img_i, a_0 = 0
    float A = 1.f, Bv = 0.f;
    #pragma unroll
    for (int i = 0; i < 8; ++i) {
        float a = v[i];
        if (lane == 0 && i == 0) a = 0.f;
        Bv = a * Bv + (1.f - a) * x[i];
        A *= a;
    }
    #pragma unroll
    for (int d = 1; d < 64; d <<= 1) {
        float Ap = __shfl_up(A, d);
        float Bp = __shfl_up(Bv, d);
        if (lane >= d) { Bv = A * Bp + Bv; A *= Ap; }
    }
    float carry = __shfl_up(Bv, 1);
    if (lane == 0) carry = 0.f;
    float xp = carry;
    #pragma unroll
    for (int i = 0; i < 8; ++i) {
        float a = v[i];
        if (lane == 0 && i == 0) a = 0.f;
        xp = a * xp + (1.f - a) * x[i];
        x[i] = xp;
    }
    // backward: y_i = a'_i y_{i+1} + (1-a'_i) x_i, a'_i = V_{i+1}, a'_511 = 0
    float vn = __shfl_down(v[0], 1);
    float A2 = 1.f, B2 = 0.f;
    #pragma unroll
    for (int i = 7; i >= 0; --i) {
        float a = (i < 7) ? v[i + 1] : ((lane == 63) ? 0.f : vn);
        B2 = a * B2 + (1.f - a) * x[i];
        A2 *= a;
    }
    #pragma unroll
    for (int d = 1; d < 64; d <<= 1) {
        float Ap = __shfl_down(A2, d);
        float Bp = __shfl_down(B2, d);
        if (lane < 64 - d) { B2 = A2 * Bp + B2; A2 *= Ap; }
    }
    float cb = __shfl_down(B2, 1);
    if (lane == 63) cb = 0.f;
    float yn = cb;
    #pragma unroll
    for (int i = 7; i >= 0; --i) {
        float a = (i < 7) ? v[i + 1] : ((lane == 63) ? 0.f : vn);
        yn = a * yn + (1.f - a) * x[i];
        x[i] = yn;
    }
}

// ---- V tables in both orientations: v = exp(c*(1+150*edge)), + transpose ----
__global__ __launch_bounds__(256) void vtab_t_kernel(const float* __restrict__ edge,
                                                     float* __restrict__ v0,
                                                     float* __restrict__ v1,
                                                     float* __restrict__ v0t,
                                                     float* __restrict__ v1t) {
    __shared__ float T0[64][65], T1[64][65];
    const int t  = threadIdx.x;
    const int i  = t & 15;                 // col quad within tile
    const int q  = t >> 4;                 // 0..15
    const int b  = blockIdx.x >> 6;
    const int tt = blockIdx.x & 63;
    const int h0 = (tt >> 3) << 6;
    const int w0 = (tt & 7) << 6;
    const size_t ib = (size_t)b << 18;
    #pragma unroll
    for (int rr = 0; rr < 4; ++rr) {
        const int r = q + (rr << 4);       // 0..63
        const size_t off = ib + ((size_t)(h0 + r) << 9) + w0 + (i << 2);
        float4 e = *reinterpret_cast<const float4*>(edge + off);
        float4 a0, a1; float d;
        d = 1.f + 150.f * e.x; a0.x = expf(C0F*d); a1.x = expf(C1F*d);
        d = 1.f + 150.f * e.y; a0.y = expf(C0F*d); a1.y = expf(C1F*d);
        d = 1.f + 150.f * e.z; a0.z = expf(C0F*d); a1.z = expf(C1F*d);
        d = 1.f + 150.f * e.w; a0.w = expf(C0F*d); a1.w = expf(C1F*d);
        *reinterpret_cast<float4*>(v0 + off) = a0;
        *reinterpret_cast<float4*>(v1 + off) = a1;
        const int c = i << 2;
        T0[r][c+0]=a0.x; T0[r][c+1]=a0.y; T0[r][c+2]=a0.z; T0[r][c+3]=a0.w;
        T1[r][c+0]=a1.x; T1[r][c+1]=a1.y; T1[r][c+2]=a1.z; T1[r][c+3]=a1.w;
    }
    __syncthreads();
    #pragma unroll
    for (int rr = 0; rr < 4; ++rr) {
        const int w = q + (rr << 4);       // 0..63 (output row = orig col)
        const int c = i << 2;
        float4 o0, o1;
        o0.x=T0[c+0][w]; o0.y=T0[c+1][w]; o0.z=T0[c+2][w]; o0.w=T0[c+3][w];
        o1.x=T1[c+0][w]; o1.y=T1[c+1][w]; o1.z=T1[c+2][w]; o1.w=T1[c+3][w];
        const size_t off = ib + ((size_t)(w0 + w) << 9) + h0 + c;
        *reinterpret_cast<float4*>(v0t + off) = o0;
        *reinterpret_cast<float4*>(v1t + off) = o1;
    }
}

// ---- Row-scan pass with transposed output --------------------------------
// Block: 64 rows x 512 tile of one (b,c) image. 8 waves x 8 rows each.
// LDS swizzle: pixel (r,c) stored at r*512 + ((c + 8*(r>>3)) & 511).
template <typename ST, typename DT>
__global__ __launch_bounds__(512) void rs_pass(const ST* __restrict__ src,
                                               DT* __restrict__ dst,
                                               const float* __restrict__ vt) {
    __shared__ h16 tile[64 * 512];
    const int lane = threadIdx.x & 63;
    const int wv   = threadIdx.x >> 6;     // 0..7
    const int bc   = blockIdx.x >> 3;
    const int b    = bc >> 5;
    const int rho0 = (blockIdx.x & 7) << 6;
    const ST*    sb = src + ((size_t)bc << 18);
    const float* vb = vt  + ((size_t)b  << 18);

    #pragma unroll
    for (int k = 0; k < 8; ++k) {
        const int r   = (wv << 3) + k;     // local row 0..63
        const int row = rho0 + r;
        float x[8], v[8];
        load8(sb + ((size_t)row << 9) + (lane << 3), x);
        load8(vb + ((size_t)row << 9) + (lane << 3), v);
        row_scan(x, v, lane);
        f16x8 hx;
        #pragma unroll
        for (int i = 0; i < 8; ++i) hx[i] = (h16)x[i];
        const int cc = (((lane + wv) & 63) << 3);   // swizzled col of px 8*lane
        *reinterpret_cast<f16x8*>(&tile[r * 512 + cc]) = hx;
    }
    __syncthreads();
    // transposed write: wave wv owns output rows c in [64*wv, 64*wv+64)
    const int g = lane >> 3;               // 0..7: row subgroup
    const int j = lane & 7;                // 16B chunk (8 h-elements) of out row
    #pragma unroll
    for (int m = 0; m < 8; ++m) {
        const int c = (wv << 6) + (m << 3) + g;     // output row (orig col)
        float y[8];
        #pragma unroll
        for (int k = 0; k < 8; ++k) {
            const int rr = (j << 3) + k;            // rr>>3 == j
            y[k] = (float)tile[rr * 512 + ((c + (j << 3)) & 511)];
        }
        store8(dst + ((size_t)bc << 18) + ((size_t)c << 9) + rho0 + (j << 3), y);
    }
}

// ================= fallback paths (R2 structure) =============================
__global__ __launch_bounds__(256) void vtab_kernel(const float* __restrict__ edge,
                                                   float* __restrict__ v0,
                                                   float* __restrict__ v1) {
    int i = blockIdx.x * 256 + threadIdx.x;
    float4 e = reinterpret_cast<const float4*>(edge)[i];
    float dx = 1.f + 150.f * e.x;
    float dy = 1.f + 150.f * e.y;
    float dz = 1.f + 150.f * e.z;
    float dw = 1.f + 150.f * e.w;
    float4 a0, a1;
    a0.x = expf(C0F * dx); a0.y = expf(C0F * dy); a0.z = expf(C0F * dz); a0.w = expf(C0F * dw);
    a1.x = expf(C1F * dx); a1.y = expf(C1F * dy); a1.z = expf(C1F * dz); a1.w = expf(C1F * dw);
    reinterpret_cast<float4*>(v0)[i] = a0;
    reinterpret_cast<float4*>(v1)[i] = a1;
}

template <typename ST, typename DT>
__global__ __launch_bounds__(256) void hpass_kernel(const ST* __restrict__ src,
                                                    DT* __restrict__ dst,
                                                    const float* __restrict__ vt) {
    const int lane = threadIdx.x & 63;
    const int wv   = threadIdx.x >> 6;
    const int row  = (blockIdx.x << 2) + wv;
    const int h    = row & (NH - 1);
    const int bc   = row >> 9;
    const int b    = bc >> 5;
    const ST* srow = src + ((size_t)row << 9);
    DT*       drow = dst + ((size_t)row << 9);
    const float* vrow = vt + (((size_t)(b << 9) + h) << 9);
    const int g0 = lane << 3;
    float x[8], v[8];
    load8(srow + g0, x);
    load8(vrow + g0, v);
    row_scan(x, v, lane);
    store8(drow + g0, x);
}

#define VROWS 32
template <typename ST, typename DT>
__global__ __launch_bounds__(512) void vpass_kernel(const ST* __restrict__ src,
                                                    DT* __restrict__ dst,
                                                    const float* __restrict__ vt) {
    const int col   = threadIdx.x & 31;
    const int hc    = threadIdx.x >> 5;
    const int strip = blockIdx.x & 15;
    const int bc    = blockIdx.x >> 4;
    const int b     = bc >> 5;
    const int w     = (strip << 5) + col;
    const ST*    sbase = src + ((size_t)bc << 18) + w;
    DT*          dbase = dst + ((size_t)bc << 18) + w;
    const float* vb    = vt  + ((size_t)b  << 18) + w;
    const int h0 = hc << 5;
    float x[VROWS], v[VROWS];
    #pragma unroll
    for (int i = 0; i < VROWS; ++i) x[i] = (float)sbase[(size_t)(h0 + i) << 9];
    #pragma unroll
    for (int i = 0; i < VROWS; ++i) v[i] = vb[(size_t)(h0 + i) << 9];
    __shared__ float sA[16][32], sB[16][32], sC[16][32], sV[16][32];
    float A = 1.f, Bv = 0.f;
    #pragma unroll
    for (int i = 0; i < VROWS; ++i) {
        float a = v[i];
        if (hc == 0 && i == 0) a = 0.f;
        Bv = a * Bv + (1.f - a) * x[i];
        A *= a;
    }
    sA[hc][col] = A; sB[hc][col] = Bv;
    __syncthreads();
    if (hc == 0) {
        float cr = 0.f;
        #pragma unroll
        for (int k = 0; k < 16; ++k) {
            float a_ = sA[k][col], b_ = sB[k][col];
            sC[k][col] = cr;
            cr = a_ * cr + b_;
        }
    }
    __syncthreads();
    float xp = sC[hc][col];
    #pragma unroll
    for (int i = 0; i < VROWS; ++i) {
        float a = v[i];
        if (hc == 0 && i == 0) a = 0.f;
        xp = a * xp + (1.f - a) * x[i];
        x[i] = xp;
    }
    sV[hc][col] = v[0];
    __syncthreads();
    float vnext = (hc < 15) ? sV[hc + 1][col] : 0.f;
    A = 1.f; Bv = 0.f;
    #pragma unroll
    for (int i = VROWS - 1; i >= 0; --i) {
        float a = (i < VROWS - 1) ? v[i + 1] : ((hc == 15) ? 0.f : vnext);
        Bv = a * Bv + (1.f - a) * x[i];
        A *= a;
    }
    sA[hc][col] = A; sB[hc][col] = Bv;
    __syncthreads();
    if (hc == 0) {
        float cr = 0.f;
        #pragma unroll
        for (int k = 15; k >= 0; --k) {
            float a_ = sA[k][col], b_ = sB[k][col];
            sC[k][col] = cr;
            cr = a_ * cr + b_;
        }
    }
    __syncthreads();
    float yn = sC[hc][col];
    #pragma unroll
    for (int i = VROWS - 1; i >= 0; --i) {
        float a = (i < VROWS - 1) ? v[i + 1] : ((hc == 15) ? 0.f : vnext);
        yn = a * yn + (1.f - a) * x[i];
        x[i] = yn;
    }
    #pragma unroll
    for (int i = 0; i < VROWS; ++i) dbase[(size_t)(h0 + i) << 9] = (DT)x[i];
}

extern "C" void kernel_launch(void* const* d_in, const int* in_sizes, int n_in,
                              void* d_out, int out_size, void* d_ws, size_t ws_size,
                              hipStream_t stream) {
    const float* img  = (const float*)d_in[0];   // [4,32,512,512]
    const float* edge = (const float*)d_in[1];   // [4,1,512,512]
    float* out = (float*)d_out;

    const size_t NBHW = (size_t)NB * NH * NW;      // 1M
    const size_t NTOT = (size_t)NB * NC * NH * NW; // 32M
    float* v0  = (float*)d_ws;
    float* v1  = v0  + NBHW;
    float* v0t = v1  + NBHW;
    float* v1t = v0t + NBHW;
    h16*   tA  = (h16*)(v1t + NBHW);               // 64 MB
    h16*   tB  = (h16*)d_out;                      // reuse out as P2->P3 scratch
    const size_t needNew = NBHW * 16 + NTOT * 2;   // 80 MB
    const size_t needT2  = NBHW * 8  + NTOT * 2;   // 72 MB

    if (ws_size >= needNew) {
        vtab_t_kernel<<<NB * 64, 256, 0, stream>>>(edge, v0, v1, v0t, v1t);
        const int G = NB * NC * 8;                 // 1024 blocks
        rs_pass<float, h16><<<G, 512, 0, stream>>>(img, tA, v0);   // H it0 -> [w][h]
        rs_pass<h16,  h16><<<G, 512, 0, stream>>>(tA, tB, v0t);    // V it0 -> [h][w]
        rs_pass<h16,  h16><<<G, 512, 0, stream>>>(tB, tA, v1);     // H it1 -> [w][h]
        rs_pass<h16, float><<<G, 512, 0, stream>>>(tA, out, v1t);  // V it1 -> [h][w]
    } else if (ws_size >= needT2) {
        h16* tmp = (h16*)(v0t);                    // only v0,v1 used in this tier
        vtab_kernel<<<(int)(NBHW / (256 * 4)), 256, 0, stream>>>(edge, v0, v1);
        const int HG = NB * NC * NH / 4;
        const int VG = NB * NC * (NW / 32);
        hpass_kernel<float, h16><<<HG, 256, 0, stream>>>(img, tmp, v0);
        vpass_kernel<h16, h16><<<VG, 512, 0, stream>>>(tmp, tmp, v0);
        hpass_kernel<h16, h16><<<HG, 256, 0, stream>>>(tmp, tmp, v1);
        vpass_kernel<h16, float><<<VG, 512, 0, stream>>>(tmp, out, v1);
    } else {
        vtab_kernel<<<(int)(NBHW / (256 * 4)), 256, 0, stream>>>(edge, v0, v1);
        const int HG = NB * NC * NH / 4;
        const int VG = NB * NC * (NW / 32);
        hpass_kernel<float, float><<<HG, 256, 0, stream>>>(img, out, v0);
        vpass_kernel<float, float><<<VG, 512, 0, stream>>>(out, out, v0);
        hpass_kernel<float, float><<<HG, 256, 0, stream>>>(out, out, v1);
        vpass_kernel<float, float><<<VG, 512, 0, stream>>>(out, out, v1);
    }
}